// Round 2
// baseline (1801.461 us; speedup 1.0000x reference)
//
#include <hip/hip_runtime.h>
#include <math.h>

// Problem constants (B=1, S=2048, H=1024, E=8, F=3584, K=2)
namespace {
constexpr int kT = 2048;   // tokens
constexpr int kH = 1024;   // hidden
constexpr int kE = 8;      // experts
constexpr int kF = 3584;   // ffn dim
constexpr int kK = 2;      // top-k

constexpr int TT = 64;     // M tile (tokens / pairs)
constexpr int TF = 64;     // N tile (f or h)
constexpr int KC = 32;     // K chunk

// workspace layout (bytes)
constexpr size_t OFF_CNT  = 0;                              // int[8]
constexpr size_t OFF_LIST = 1024;                           // int[8][2048]
constexpr size_t OFF_RW   = OFF_LIST + sizeof(int) * kE * kT; // float[4096]
constexpr size_t OFF_HMID = 1u << 20;                       // float[4096][3584]
}

// ---------------------------------------------------------------------------
// Router: logits = x @ gate_w.T ; softmax; top-2; normalized weights;
// per-expert compacted pair lists. 1 block (256 thr) per token.
// ---------------------------------------------------------------------------
__global__ __launch_bounds__(256) void router_kernel(
    const float* __restrict__ x, const float* __restrict__ gw,
    float* __restrict__ logits_out, int* __restrict__ cnt,
    int* __restrict__ list, float* __restrict__ rw) {
  const int t = blockIdx.x;
  const float* xt = x + (size_t)t * kH;
  __shared__ float lg[kE];
  const int wave = threadIdx.x >> 6;
  const int lane = threadIdx.x & 63;
  for (int e = wave; e < kE; e += 4) {
    const float* g = gw + (size_t)e * kH;
    float s = 0.f;
    for (int h = lane; h < kH; h += 64) s += xt[h] * g[h];
#pragma unroll
    for (int off = 32; off > 0; off >>= 1) s += __shfl_down(s, off, 64);
    if (lane == 0) lg[e] = s;
  }
  __syncthreads();
  if (threadIdx.x < kE) logits_out[(size_t)t * kE + threadIdx.x] = lg[threadIdx.x];
  if (threadIdx.x == 0) {
    float m = lg[0];
#pragma unroll
    for (int e = 1; e < kE; ++e) m = fmaxf(m, lg[e]);
    float p[kE];
#pragma unroll
    for (int e = 0; e < kE; ++e) p[e] = expf(lg[e] - m);
    // top-2 with first-index tie-break (strict >), matching jax.lax.top_k
    int i0 = 0;
#pragma unroll
    for (int e = 1; e < kE; ++e) if (p[e] > p[i0]) i0 = e;
    int i1 = (i0 == 0) ? 1 : 0;
#pragma unroll
    for (int e = 0; e < kE; ++e)
      if (e != i0 && e != i1 && p[e] > p[i1]) i1 = e;
    const float w0 = p[i0], w1v = p[i1];
    const float inv = 1.f / (w0 + w1v);
    rw[t * kK + 0] = w0 * inv;
    rw[t * kK + 1] = w1v * inv;
    const int s0 = atomicAdd(&cnt[i0], 1);
    list[i0 * kT + s0] = t * kK + 0;
    const int s1 = atomicAdd(&cnt[i1], 1);
    list[i1 * kT + s1] = t * kK + 1;
  }
}

// ---------------------------------------------------------------------------
// GEMM1: hmid[p, f] = silu(x[t] . w1[e][f]) * (x[t] . w3[e][f])
// gathered rows per expert; 64x64 tile, 4x4 micro, K-chunk 32, LDS [K][M].
// ---------------------------------------------------------------------------
__global__ __launch_bounds__(256) void moe_mid_kernel(
    const float* __restrict__ x, const float* __restrict__ w1,
    const float* __restrict__ w3, const int* __restrict__ cnt,
    const int* __restrict__ list, float* __restrict__ hmid) {
  const int e = blockIdx.z;
  const int n = cnt[e];
  const int t0 = blockIdx.y * TT;
  if (t0 >= n) return;
  const int f0 = blockIdx.x * TF;

  __shared__ float xs[KC][TT];
  __shared__ float w1s[KC][TF];
  __shared__ float w3s[KC][TF];
  __shared__ int prs[TT];

  if (threadIdx.x < TT) {
    const int idx = t0 + threadIdx.x;
    prs[threadIdx.x] = (idx < n) ? list[e * kT + idx] : -1;
  }
  __syncthreads();

  const float* w1e = w1 + (size_t)e * kF * kH;
  const float* w3e = w3 + (size_t)e * kF * kH;

  float acc1[4][4] = {{0.f}};
  float acc3[4][4] = {{0.f}};
  const int tx = (threadIdx.x & 15) * 4;
  const int ty = (threadIdx.x >> 4) * 4;

  for (int k0 = 0; k0 < kH; k0 += KC) {
    __syncthreads();
#pragma unroll
    for (int r = 0; r < 2; ++r) {
      const int el = threadIdx.x + 256 * r;
      const int row = el >> 3;           // 0..63
      const int c = (el & 7) * 4;        // 0..28
      {
        const int pid = prs[row];
        float4 v = make_float4(0.f, 0.f, 0.f, 0.f);
        if (pid >= 0)
          v = *reinterpret_cast<const float4*>(x + (size_t)(pid >> 1) * kH + k0 + c);
        xs[c + 0][row] = v.x; xs[c + 1][row] = v.y;
        xs[c + 2][row] = v.z; xs[c + 3][row] = v.w;
      }
      {
        const float4 v = *reinterpret_cast<const float4*>(
            w1e + (size_t)(f0 + row) * kH + k0 + c);
        w1s[c + 0][row] = v.x; w1s[c + 1][row] = v.y;
        w1s[c + 2][row] = v.z; w1s[c + 3][row] = v.w;
      }
      {
        const float4 v = *reinterpret_cast<const float4*>(
            w3e + (size_t)(f0 + row) * kH + k0 + c);
        w3s[c + 0][row] = v.x; w3s[c + 1][row] = v.y;
        w3s[c + 2][row] = v.z; w3s[c + 3][row] = v.w;
      }
    }
    __syncthreads();
#pragma unroll
    for (int kk = 0; kk < KC; ++kk) {
      const float4 a  = *reinterpret_cast<const float4*>(&xs[kk][ty]);
      const float4 b1 = *reinterpret_cast<const float4*>(&w1s[kk][tx]);
      const float4 b3 = *reinterpret_cast<const float4*>(&w3s[kk][tx]);
      const float av[4]  = {a.x, a.y, a.z, a.w};
      const float b1v[4] = {b1.x, b1.y, b1.z, b1.w};
      const float b3v[4] = {b3.x, b3.y, b3.z, b3.w};
#pragma unroll
      for (int i = 0; i < 4; ++i)
#pragma unroll
        for (int j = 0; j < 4; ++j) {
          acc1[i][j] += av[i] * b1v[j];
          acc3[i][j] += av[i] * b3v[j];
        }
    }
  }

#pragma unroll
  for (int i = 0; i < 4; ++i) {
    const int pid = prs[ty + i];
    if (pid < 0) continue;
    float* hp = hmid + (size_t)pid * kF + f0 + tx;
#pragma unroll
    for (int j = 0; j < 4; ++j) {
      const float s1 = acc1[i][j];
      const float s3 = acc3[i][j];
      const float sig = 1.f / (1.f + expf(-s1));
      hp[j] = (s1 * sig) * s3;
    }
  }
}

// ---------------------------------------------------------------------------
// GEMM2: out[t, h] += rw[p] * (hmid[p] . w2[e][h])   (2 commutative atomics)
// ---------------------------------------------------------------------------
__global__ __launch_bounds__(256) void moe_out_kernel(
    const float* __restrict__ hmid, const float* __restrict__ w2,
    const int* __restrict__ cnt, const int* __restrict__ list,
    const float* __restrict__ rw, float* __restrict__ out) {
  const int e = blockIdx.z;
  const int n = cnt[e];
  const int p0 = blockIdx.y * TT;
  if (p0 >= n) return;
  const int h0 = blockIdx.x * TF;

  __shared__ float as_[KC][TT];
  __shared__ float bs[KC][TF];
  __shared__ int prs[TT];

  if (threadIdx.x < TT) {
    const int idx = p0 + threadIdx.x;
    prs[threadIdx.x] = (idx < n) ? list[e * kT + idx] : -1;
  }
  __syncthreads();

  const float* w2e = w2 + (size_t)e * kH * kF;

  float acc[4][4] = {{0.f}};
  const int tx = (threadIdx.x & 15) * 4;
  const int ty = (threadIdx.x >> 4) * 4;

  for (int k0 = 0; k0 < kF; k0 += KC) {
    __syncthreads();
#pragma unroll
    for (int r = 0; r < 2; ++r) {
      const int el = threadIdx.x + 256 * r;
      const int row = el >> 3;
      const int c = (el & 7) * 4;
      {
        const int pid = prs[row];
        float4 v = make_float4(0.f, 0.f, 0.f, 0.f);
        if (pid >= 0)
          v = *reinterpret_cast<const float4*>(hmid + (size_t)pid * kF + k0 + c);
        as_[c + 0][row] = v.x; as_[c + 1][row] = v.y;
        as_[c + 2][row] = v.z; as_[c + 3][row] = v.w;
      }
      {
        const float4 v = *reinterpret_cast<const float4*>(
            w2e + (size_t)(h0 + row) * kF + k0 + c);
        bs[c + 0][row] = v.x; bs[c + 1][row] = v.y;
        bs[c + 2][row] = v.z; bs[c + 3][row] = v.w;
      }
    }
    __syncthreads();
#pragma unroll
    for (int kk = 0; kk < KC; ++kk) {
      const float4 a = *reinterpret_cast<const float4*>(&as_[kk][ty]);
      const float4 b = *reinterpret_cast<const float4*>(&bs[kk][tx]);
      const float av[4] = {a.x, a.y, a.z, a.w};
      const float bv[4] = {b.x, b.y, b.z, b.w};
#pragma unroll
      for (int i = 0; i < 4; ++i)
#pragma unroll
        for (int j = 0; j < 4; ++j)
          acc[i][j] += av[i] * bv[j];
    }
  }

#pragma unroll
  for (int i = 0; i < 4; ++i) {
    const int pid = prs[ty + i];
    if (pid < 0) continue;
    const int tok = pid >> 1;
    const float w = rw[pid];
    float* op = out + (size_t)tok * kH + h0 + tx;
#pragma unroll
    for (int j = 0; j < 4; ++j)
      atomicAdd(&op[j], w * acc[i][j]);
  }
}

// ---------------------------------------------------------------------------
extern "C" void kernel_launch(void* const* d_in, const int* in_sizes, int n_in,
                              void* d_out, int out_size, void* d_ws,
                              size_t ws_size, hipStream_t stream) {
  (void)in_sizes; (void)n_in; (void)out_size; (void)ws_size;
  const float* x  = (const float*)d_in[0];  // [1,2048,1024]
  const float* gw = (const float*)d_in[1];  // [8,1024]
  const float* w1 = (const float*)d_in[2];  // [8,3584,1024]
  const float* w2 = (const float*)d_in[3];  // [8,1024,3584]
  const float* w3 = (const float*)d_in[4];  // [8,3584,1024]

  float* out    = (float*)d_out;                 // [2048*1024]
  float* logits = out + (size_t)kT * kH;         // [2048*8]

  char* ws = (char*)d_ws;
  int*   cnt  = (int*)(ws + OFF_CNT);
  int*   list = (int*)(ws + OFF_LIST);
  float* rw   = (float*)(ws + OFF_RW);
  float* hmid = (float*)(ws + OFF_HMID);

  hipMemsetAsync(out, 0, (size_t)kT * kH * sizeof(float), stream);
  hipMemsetAsync(cnt, 0, kE * sizeof(int), stream);

  router_kernel<<<kT, 256, 0, stream>>>(x, gw, logits, cnt, list, rw);

  dim3 g1(kF / TF, kT / TT, kE);   // (56, 32, 8)
  moe_mid_kernel<<<g1, 256, 0, stream>>>(x, w1, w3, cnt, list, hmid);

  dim3 g2(kH / TF, kT / TT, kE);   // (16, 32, 8)
  moe_out_kernel<<<g2, 256, 0, stream>>>(hmid, w2, cnt, list, rw, out);
}

// Round 3
// 496.162 us; speedup vs baseline: 3.6308x; 3.6308x over previous
//
#include <hip/hip_runtime.h>
#include <math.h>

// Problem constants (B=1, S=2048, H=1024, E=8, F=3584, K=2)
namespace {
constexpr int kT = 2048;   // tokens
constexpr int kH = 1024;   // hidden
constexpr int kE = 8;      // experts
constexpr int kF = 3584;   // ffn dim
constexpr int kK = 2;      // top-k

// workspace layout (bytes)
constexpr size_t OFF_CNT  = 0;                                // int[8]
constexpr size_t OFF_LIST = 1024;                             // int[8][2048]
constexpr size_t OFF_RW   = OFF_LIST + sizeof(int) * kE * kT; // float[4096]
constexpr size_t OFF_HMID = 1u << 20;                         // bf16[4096][3584] = 28.7 MB

typedef __attribute__((ext_vector_type(8))) short bf16x8;     // 8 bf16 in 4 VGPRs
typedef __attribute__((ext_vector_type(4))) float fx4;
}

// f32 -> bf16 round-nearest-even
__device__ __forceinline__ unsigned short f2bf(float f) {
  union { float f; unsigned u; } v; v.f = f;
  return (unsigned short)((v.u + 0x7fffu + ((v.u >> 16) & 1u)) >> 16);
}

__device__ __forceinline__ bf16x8 pack8(float4 a, float4 b) {
  bf16x8 r;
  r[0] = (short)f2bf(a.x); r[1] = (short)f2bf(a.y);
  r[2] = (short)f2bf(a.z); r[3] = (short)f2bf(a.w);
  r[4] = (short)f2bf(b.x); r[5] = (short)f2bf(b.y);
  r[6] = (short)f2bf(b.z); r[7] = (short)f2bf(b.w);
  return r;
}

// ---------------------------------------------------------------------------
// Router (f32, exact — expert selection must not move): logits, softmax,
// top-2 (strict > tie-break = jax.lax.top_k), normalized weights, per-expert
// compacted pair lists. 1 block per token.
// ---------------------------------------------------------------------------
__global__ __launch_bounds__(256) void router_kernel(
    const float* __restrict__ x, const float* __restrict__ gw,
    float* __restrict__ logits_out, int* __restrict__ cnt,
    int* __restrict__ list, float* __restrict__ rw) {
  const int t = blockIdx.x;
  const float* xt = x + (size_t)t * kH;
  __shared__ float lg[kE];
  const int wave = threadIdx.x >> 6;
  const int lane = threadIdx.x & 63;
  for (int e = wave; e < kE; e += 4) {
    const float* g = gw + (size_t)e * kH;
    float s = 0.f;
    for (int h = lane; h < kH; h += 64) s += xt[h] * g[h];
#pragma unroll
    for (int off = 32; off > 0; off >>= 1) s += __shfl_down(s, off, 64);
    if (lane == 0) lg[e] = s;
  }
  __syncthreads();
  if (threadIdx.x < kE) logits_out[(size_t)t * kE + threadIdx.x] = lg[threadIdx.x];
  if (threadIdx.x == 0) {
    float m = lg[0];
#pragma unroll
    for (int e = 1; e < kE; ++e) m = fmaxf(m, lg[e]);
    float p[kE];
#pragma unroll
    for (int e = 0; e < kE; ++e) p[e] = expf(lg[e] - m);
    int i0 = 0;
#pragma unroll
    for (int e = 1; e < kE; ++e) if (p[e] > p[i0]) i0 = e;
    int i1 = (i0 == 0) ? 1 : 0;
#pragma unroll
    for (int e = 0; e < kE; ++e)
      if (e != i0 && e != i1 && p[e] > p[i1]) i1 = e;
    const float w0 = p[i0], w1v = p[i1];
    const float inv = 1.f / (w0 + w1v);
    rw[t * kK + 0] = w0 * inv;
    rw[t * kK + 1] = w1v * inv;
    const int s0 = atomicAdd(&cnt[i0], 1);
    list[i0 * kT + s0] = t * kK + 0;
    const int s1 = atomicAdd(&cnt[i1], 1);
    list[i1 * kT + s1] = t * kK + 1;
  }
}

// ---------------------------------------------------------------------------
// GEMM1 (MFMA): hmid_bf16[p, f] = bf16( silu(x[t].w1[e][f]) * (x[t].w3[e][f]) )
// Tile 128(pairs) x 64(f), BK=32, 4 waves (2x2), wave tile 64x32.
// A: gathered x rows, f32->bf16 reg-staged. B1/B3: w rows, f32->bf16 staged.
// mfma_f32_16x16x32_bf16; A/B frag: row=lane&15, k=(lane>>4)*8+j;
// C/D: col=lane&15, row=(lane>>4)*4+i  [m89-verified].
// ---------------------------------------------------------------------------
__global__ __launch_bounds__(256) void moe_mid_mfma(
    const float* __restrict__ x, const float* __restrict__ w1,
    const float* __restrict__ w3, const int* __restrict__ cnt,
    const int* __restrict__ list, unsigned short* __restrict__ hmid) {
  const int e = blockIdx.z;
  const int n = cnt[e];
  const int t0 = blockIdx.y * 128;
  if (t0 >= n) return;
  const int f0 = blockIdx.x * 64;

  __shared__ short As[128 * 32];
  __shared__ short B1s[64 * 32];
  __shared__ short B3s[64 * 32];
  __shared__ int ptok[128];
  __shared__ int ppid[128];

  const int tid = threadIdx.x;
  if (tid < 128) {
    const int idx = t0 + tid;
    const int pid = (idx < n) ? list[e * kT + idx] : -1;
    ppid[tid] = pid;
    ptok[tid] = (pid < 0) ? 0 : (pid >> 1);
  }
  __syncthreads();

  const float* w1e = w1 + (size_t)e * kF * kH;
  const float* w3e = w3 + (size_t)e * kF * kH;

  const int lane = tid & 63;
  const int wid = tid >> 6;
  const int wr = wid >> 1, wc = wid & 1;     // wave grid 2x2
  const int lr = lane & 15, lq = lane >> 4;

  fx4 acc1[4][2], acc3[4][2];
#pragma unroll
  for (int i = 0; i < 4; ++i)
#pragma unroll
    for (int j = 0; j < 2; ++j) {
      acc1[i][j] = (fx4)(0.f);
      acc3[i][j] = (fx4)(0.f);
    }

  // staging indices: A 16 elems/thread, B 8 elems/thread
  const int ar = tid >> 1, aq = (tid & 1) * 16;
  const int br = tid >> 2, bq = (tid & 3) * 8;
  const float* axp = x + (size_t)ptok[ar] * kH + aq;

  for (int k0 = 0; k0 < kH; k0 += 32) {
    {  // A
      const float4* ap = reinterpret_cast<const float4*>(axp + k0);
      const float4 v0 = ap[0], v1 = ap[1], v2 = ap[2], v3 = ap[3];
      *reinterpret_cast<bf16x8*>(&As[ar * 32 + aq])     = pack8(v0, v1);
      *reinterpret_cast<bf16x8*>(&As[ar * 32 + aq + 8]) = pack8(v2, v3);
    }
    {  // B1
      const float4* bp = reinterpret_cast<const float4*>(
          w1e + (size_t)(f0 + br) * kH + k0 + bq);
      *reinterpret_cast<bf16x8*>(&B1s[br * 32 + bq]) = pack8(bp[0], bp[1]);
    }
    {  // B3
      const float4* bp = reinterpret_cast<const float4*>(
          w3e + (size_t)(f0 + br) * kH + k0 + bq);
      *reinterpret_cast<bf16x8*>(&B3s[br * 32 + bq]) = pack8(bp[0], bp[1]);
    }
    __syncthreads();

    bf16x8 a[4], b1f[2], b3f[2];
#pragma unroll
    for (int mi = 0; mi < 4; ++mi)
      a[mi] = *reinterpret_cast<const bf16x8*>(
          &As[(wr * 64 + mi * 16 + lr) * 32 + lq * 8]);
#pragma unroll
    for (int ni = 0; ni < 2; ++ni) {
      b1f[ni] = *reinterpret_cast<const bf16x8*>(
          &B1s[(wc * 32 + ni * 16 + lr) * 32 + lq * 8]);
      b3f[ni] = *reinterpret_cast<const bf16x8*>(
          &B3s[(wc * 32 + ni * 16 + lr) * 32 + lq * 8]);
    }
#pragma unroll
    for (int mi = 0; mi < 4; ++mi)
#pragma unroll
      for (int ni = 0; ni < 2; ++ni) {
        acc1[mi][ni] = __builtin_amdgcn_mfma_f32_16x16x32_bf16(
            a[mi], b1f[ni], acc1[mi][ni], 0, 0, 0);
        acc3[mi][ni] = __builtin_amdgcn_mfma_f32_16x16x32_bf16(
            a[mi], b3f[ni], acc3[mi][ni], 0, 0, 0);
      }
    __syncthreads();
  }

#pragma unroll
  for (int mi = 0; mi < 4; ++mi)
#pragma unroll
    for (int i = 0; i < 4; ++i) {
      const int row = wr * 64 + mi * 16 + lq * 4 + i;
      const int pid = ppid[row];
      if (pid < 0) continue;
#pragma unroll
      for (int ni = 0; ni < 2; ++ni) {
        const int col = f0 + wc * 32 + ni * 16 + lr;
        const float s1 = acc1[mi][ni][i];
        const float s3 = acc3[mi][ni][i];
        const float h = s1 * s3 / (1.f + expf(-s1));  // silu(s1)*s3
        hmid[(size_t)pid * kF + col] = f2bf(h);
      }
    }
}

// ---------------------------------------------------------------------------
// GEMM2 (MFMA): out[t,:] += rw[p] * (hmid_bf16[p] . w2[e][h])
// Tile 128(pairs) x 64(h), BK=32. A: hmid bf16 direct. B: w2 f32->bf16.
// Epilogue: 2 commutative f32 atomics per out element -> deterministic.
// ---------------------------------------------------------------------------
__global__ __launch_bounds__(256) void moe_out_mfma(
    const unsigned short* __restrict__ hmid, const float* __restrict__ w2,
    const int* __restrict__ cnt, const int* __restrict__ list,
    const float* __restrict__ rw, float* __restrict__ out) {
  const int e = blockIdx.z;
  const int n = cnt[e];
  const int p0 = blockIdx.y * 128;
  if (p0 >= n) return;
  const int h0 = blockIdx.x * 64;

  __shared__ short As[128 * 32];
  __shared__ short Bs[64 * 32];
  __shared__ int prow[128];
  __shared__ int ppid[128];

  const int tid = threadIdx.x;
  if (tid < 128) {
    const int idx = p0 + tid;
    const int pid = (idx < n) ? list[e * kT + idx] : -1;
    ppid[tid] = pid;
    prow[tid] = (pid < 0) ? 0 : pid;
  }
  __syncthreads();

  const float* w2e = w2 + (size_t)e * kH * kF;

  const int lane = tid & 63;
  const int wid = tid >> 6;
  const int wr = wid >> 1, wc = wid & 1;
  const int lr = lane & 15, lq = lane >> 4;

  fx4 acc[4][2];
#pragma unroll
  for (int i = 0; i < 4; ++i)
#pragma unroll
    for (int j = 0; j < 2; ++j) acc[i][j] = (fx4)(0.f);

  const int ar = tid >> 1, aq = (tid & 1) * 16;
  const int br = tid >> 2, bq = (tid & 3) * 8;
  const unsigned short* axp = hmid + (size_t)prow[ar] * kF + aq;

  for (int k0 = 0; k0 < kF; k0 += 32) {
    {  // A (bf16 direct)
      const bf16x8* ap = reinterpret_cast<const bf16x8*>(axp + k0);
      *reinterpret_cast<bf16x8*>(&As[ar * 32 + aq])     = ap[0];
      *reinterpret_cast<bf16x8*>(&As[ar * 32 + aq + 8]) = ap[1];
    }
    {  // B (f32 -> bf16)
      const float4* bp = reinterpret_cast<const float4*>(
          w2e + (size_t)(h0 + br) * kF + k0 + bq);
      *reinterpret_cast<bf16x8*>(&Bs[br * 32 + bq]) = pack8(bp[0], bp[1]);
    }
    __syncthreads();

    bf16x8 a[4], b[2];
#pragma unroll
    for (int mi = 0; mi < 4; ++mi)
      a[mi] = *reinterpret_cast<const bf16x8*>(
          &As[(wr * 64 + mi * 16 + lr) * 32 + lq * 8]);
#pragma unroll
    for (int ni = 0; ni < 2; ++ni)
      b[ni] = *reinterpret_cast<const bf16x8*>(
          &Bs[(wc * 32 + ni * 16 + lr) * 32 + lq * 8]);
#pragma unroll
    for (int mi = 0; mi < 4; ++mi)
#pragma unroll
      for (int ni = 0; ni < 2; ++ni)
        acc[mi][ni] = __builtin_amdgcn_mfma_f32_16x16x32_bf16(
            a[mi], b[ni], acc[mi][ni], 0, 0, 0);
    __syncthreads();
  }

#pragma unroll
  for (int mi = 0; mi < 4; ++mi)
#pragma unroll
    for (int i = 0; i < 4; ++i) {
      const int row = wr * 64 + mi * 16 + lq * 4 + i;
      const int pid = ppid[row];
      if (pid < 0) continue;
      const int tok = pid >> 1;
      const float w = rw[pid];
      float* op = out + (size_t)tok * kH + h0 + wc * 32 + lr;
#pragma unroll
      for (int ni = 0; ni < 2; ++ni)
        atomicAdd(&op[ni * 16], w * acc[mi][ni][i]);
    }
}

// ---------------------------------------------------------------------------
extern "C" void kernel_launch(void* const* d_in, const int* in_sizes, int n_in,
                              void* d_out, int out_size, void* d_ws,
                              size_t ws_size, hipStream_t stream) {
  (void)in_sizes; (void)n_in; (void)out_size; (void)ws_size;
  const float* x  = (const float*)d_in[0];  // [1,2048,1024]
  const float* gw = (const float*)d_in[1];  // [8,1024]
  const float* w1 = (const float*)d_in[2];  // [8,3584,1024]
  const float* w2 = (const float*)d_in[3];  // [8,1024,3584]
  const float* w3 = (const float*)d_in[4];  // [8,3584,1024]

  float* out    = (float*)d_out;             // [2048*1024]
  float* logits = out + (size_t)kT * kH;     // [2048*8]

  char* ws = (char*)d_ws;
  int*            cnt  = (int*)(ws + OFF_CNT);
  int*            list = (int*)(ws + OFF_LIST);
  float*          rw   = (float*)(ws + OFF_RW);
  unsigned short* hmid = (unsigned short*)(ws + OFF_HMID);

  hipMemsetAsync(out, 0, (size_t)kT * kH * sizeof(float), stream);
  hipMemsetAsync(cnt, 0, kE * sizeof(int), stream);

  router_kernel<<<kT, 256, 0, stream>>>(x, gw, logits, cnt, list, rw);

  dim3 g1(kF / 64, kT / 128, kE);   // (56, 16, 8)
  moe_mid_mfma<<<g1, 256, 0, stream>>>(x, w1, w3, cnt, list, hmid);

  dim3 g2(kH / 64, kT / 128, kE);   // (16, 16, 8)
  moe_out_mfma<<<g2, 256, 0, stream>>>(hmid, w2, cnt, list, rw, out);
}

// Round 4
// 329.485 us; speedup vs baseline: 5.4675x; 1.5059x over previous
//
#include <hip/hip_runtime.h>
#include <math.h>

// Problem constants (B=1, S=2048, H=1024, E=8, F=3584, K=2)
namespace {
constexpr int kT = 2048;   // tokens
constexpr int kH = 1024;   // hidden
constexpr int kE = 8;      // experts
constexpr int kF = 3584;   // ffn dim
constexpr int kK = 2;      // top-k

// workspace layout (bytes)
constexpr size_t OFF_CNT  = 0;                                // int[8]
constexpr size_t OFF_LIST = 1024;                             // int[8][2048]
constexpr size_t OFF_RW   = OFF_LIST + sizeof(int) * kE * kT; // float[4096]
constexpr size_t OFF_HMID = 1u << 20;                         // bf16[4096][3584] = 28.7 MB

typedef __attribute__((ext_vector_type(8))) short bf16x8;     // 8 bf16 in 4 VGPRs
typedef __attribute__((ext_vector_type(4))) float fx4;
}

// f32 -> bf16 round-nearest-even
__device__ __forceinline__ unsigned short f2bf(float f) {
  union { float f; unsigned u; } v; v.f = f;
  return (unsigned short)((v.u + 0x7fffu + ((v.u >> 16) & 1u)) >> 16);
}

__device__ __forceinline__ bf16x8 pack8(float4 a, float4 b) {
  bf16x8 r;
  r[0] = (short)f2bf(a.x); r[1] = (short)f2bf(a.y);
  r[2] = (short)f2bf(a.z); r[3] = (short)f2bf(a.w);
  r[4] = (short)f2bf(b.x); r[5] = (short)f2bf(b.y);
  r[6] = (short)f2bf(b.z); r[7] = (short)f2bf(b.w);
  return r;
}

// LDS layout: [row][64 bf16] rows of 128B = 8 x 16B units; XOR-swizzle the
// 16B unit by (row&7) -> fragment reads (16 rows, fixed unit) spread across
// all 8 bank-quads (~2-way, free per m136). Applied on BOTH write and read.
__device__ __forceinline__ int swz(int row, int u) {
  return row * 64 + ((u ^ (row & 7)) << 3);   // index in shorts
}

// ---------------------------------------------------------------------------
// Router (f32, exact — expert selection must not move): logits, softmax,
// top-2 (strict > tie-break = jax.lax.top_k), normalized weights, per-expert
// compacted pair lists. 1 block per token.
// ---------------------------------------------------------------------------
__global__ __launch_bounds__(256) void router_kernel(
    const float* __restrict__ x, const float* __restrict__ gw,
    float* __restrict__ logits_out, int* __restrict__ cnt,
    int* __restrict__ list, float* __restrict__ rw) {
  const int t = blockIdx.x;
  const float* xt = x + (size_t)t * kH;
  __shared__ float lg[kE];
  const int wave = threadIdx.x >> 6;
  const int lane = threadIdx.x & 63;
  for (int e = wave; e < kE; e += 4) {
    const float* g = gw + (size_t)e * kH;
    float s = 0.f;
    for (int h = lane; h < kH; h += 64) s += xt[h] * g[h];
#pragma unroll
    for (int off = 32; off > 0; off >>= 1) s += __shfl_down(s, off, 64);
    if (lane == 0) lg[e] = s;
  }
  __syncthreads();
  if (threadIdx.x < kE) logits_out[(size_t)t * kE + threadIdx.x] = lg[threadIdx.x];
  if (threadIdx.x == 0) {
    float m = lg[0];
#pragma unroll
    for (int e = 1; e < kE; ++e) m = fmaxf(m, lg[e]);
    float p[kE];
#pragma unroll
    for (int e = 0; e < kE; ++e) p[e] = expf(lg[e] - m);
    int i0 = 0;
#pragma unroll
    for (int e = 1; e < kE; ++e) if (p[e] > p[i0]) i0 = e;
    int i1 = (i0 == 0) ? 1 : 0;
#pragma unroll
    for (int e = 0; e < kE; ++e)
      if (e != i0 && e != i1 && p[e] > p[i1]) i1 = e;
    const float w0 = p[i0], w1v = p[i1];
    const float inv = 1.f / (w0 + w1v);
    rw[t * kK + 0] = w0 * inv;
    rw[t * kK + 1] = w1v * inv;
    const int s0 = atomicAdd(&cnt[i0], 1);
    list[i0 * kT + s0] = t * kK + 0;
    const int s1 = atomicAdd(&cnt[i1], 1);
    list[i1 * kT + s1] = t * kK + 1;
  }
}

// ---------------------------------------------------------------------------
// GEMM1 (MFMA, 2-phase dbuf): hmid[p,f] = bf16(silu(x.w1)*(x.w3))
// Tile 128(pairs) x 64(f), BK=64, 4 waves (2x2), 32 MFMA/wave/iter.
// Per iter: issue next-tile global loads -> ds_read+MFMA cur -> ds_write nxt
// -> one barrier. XOR-swizzled LDS.
// ---------------------------------------------------------------------------
__global__ __launch_bounds__(256) void moe_mid_mfma(
    const float* __restrict__ x, const float* __restrict__ w1,
    const float* __restrict__ w3, const int* __restrict__ cnt,
    const int* __restrict__ list, unsigned short* __restrict__ hmid) {
  const int e = blockIdx.z;
  const int n = cnt[e];
  const int t0 = blockIdx.y * 128;
  if (t0 >= n) return;
  const int f0 = blockIdx.x * 64;

  __shared__ short As[2][128 * 64];
  __shared__ short B1s[2][64 * 64];
  __shared__ short B3s[2][64 * 64];
  __shared__ int ppid[128];
  __shared__ int ptok[128];

  const int tid = threadIdx.x;
  if (tid < 128) {
    const int idx = t0 + tid;
    const int pid = (idx < n) ? list[e * kT + idx] : -1;
    ppid[tid] = pid;
    ptok[tid] = (pid < 0) ? 0 : (pid >> 1);
  }
  __syncthreads();

  const float* w1e = w1 + (size_t)e * kF * kH;
  const float* w3e = w3 + (size_t)e * kF * kH;

  // A staging map: 4 chunks, chunk i covers (row=flat>>3, unit=flat&7)
  const float* a_src[4];
  int a_sw[4];
#pragma unroll
  for (int i = 0; i < 4; ++i) {
    const int flat = tid + 256 * i;
    const int row = flat >> 3, u = flat & 7;
    a_src[i] = x + (size_t)ptok[row] * kH + u * 8;
    a_sw[i] = swz(row, u);
  }
  // B staging map: row=tid>>2, unit-pair=tid&3
  const int brow = tid >> 2, bup = tid & 3;
  const float* b1_src = w1e + (size_t)(f0 + brow) * kH + bup * 16;
  const float* b3_src = w3e + (size_t)(f0 + brow) * kH + bup * 16;
  const int b_sw0 = swz(brow, 2 * bup), b_sw1 = swz(brow, 2 * bup + 1);

  const int lane = tid & 63, wid = tid >> 6;
  const int wr = wid >> 1, wc = wid & 1;
  const int lr = lane & 15, lq = lane >> 4;

  fx4 acc1[4][2], acc3[4][2];
#pragma unroll
  for (int i = 0; i < 4; ++i)
#pragma unroll
    for (int j = 0; j < 2; ++j) { acc1[i][j] = (fx4)(0.f); acc3[i][j] = (fx4)(0.f); }

  float4 aR[4][2], b1R[4], b3R[4];
  auto LOAD = [&](int k0) {
#pragma unroll
    for (int i = 0; i < 4; ++i) {
      aR[i][0] = *reinterpret_cast<const float4*>(a_src[i] + k0);
      aR[i][1] = *reinterpret_cast<const float4*>(a_src[i] + k0 + 4);
    }
#pragma unroll
    for (int j = 0; j < 4; ++j) {
      b1R[j] = *reinterpret_cast<const float4*>(b1_src + k0 + j * 4);
      b3R[j] = *reinterpret_cast<const float4*>(b3_src + k0 + j * 4);
    }
  };
  auto STORE = [&](int buf) {
    short* Ab = As[buf]; short* B1b = B1s[buf]; short* B3b = B3s[buf];
#pragma unroll
    for (int i = 0; i < 4; ++i)
      *reinterpret_cast<bf16x8*>(&Ab[a_sw[i]]) = pack8(aR[i][0], aR[i][1]);
    *reinterpret_cast<bf16x8*>(&B1b[b_sw0]) = pack8(b1R[0], b1R[1]);
    *reinterpret_cast<bf16x8*>(&B1b[b_sw1]) = pack8(b1R[2], b1R[3]);
    *reinterpret_cast<bf16x8*>(&B3b[b_sw0]) = pack8(b3R[0], b3R[1]);
    *reinterpret_cast<bf16x8*>(&B3b[b_sw1]) = pack8(b3R[2], b3R[3]);
  };

  LOAD(0); STORE(0); __syncthreads();
  int cur = 0;
  constexpr int NIT = kH / 64;
  for (int it = 0; it < NIT; ++it) {
    const bool pf = (it + 1 < NIT);
    if (pf) LOAD((it + 1) * 64);
    const short* Ab = As[cur]; const short* B1b = B1s[cur]; const short* B3b = B3s[cur];
    __builtin_amdgcn_s_setprio(1);
#pragma unroll
    for (int ks = 0; ks < 2; ++ks) {
      bf16x8 a[4], bb1[2], bb3[2];
#pragma unroll
      for (int mi = 0; mi < 4; ++mi)
        a[mi] = *reinterpret_cast<const bf16x8*>(&Ab[swz(wr * 64 + mi * 16 + lr, ks * 4 + lq)]);
#pragma unroll
      for (int ni = 0; ni < 2; ++ni) {
        bb1[ni] = *reinterpret_cast<const bf16x8*>(&B1b[swz(wc * 32 + ni * 16 + lr, ks * 4 + lq)]);
        bb3[ni] = *reinterpret_cast<const bf16x8*>(&B3b[swz(wc * 32 + ni * 16 + lr, ks * 4 + lq)]);
      }
#pragma unroll
      for (int mi = 0; mi < 4; ++mi)
#pragma unroll
        for (int ni = 0; ni < 2; ++ni) {
          acc1[mi][ni] = __builtin_amdgcn_mfma_f32_16x16x32_bf16(a[mi], bb1[ni], acc1[mi][ni], 0, 0, 0);
          acc3[mi][ni] = __builtin_amdgcn_mfma_f32_16x16x32_bf16(a[mi], bb3[ni], acc3[mi][ni], 0, 0, 0);
        }
    }
    __builtin_amdgcn_s_setprio(0);
    if (pf) STORE(cur ^ 1);
    __syncthreads();
    cur ^= 1;
  }

#pragma unroll
  for (int mi = 0; mi < 4; ++mi)
#pragma unroll
    for (int i = 0; i < 4; ++i) {
      const int row = wr * 64 + mi * 16 + lq * 4 + i;
      const int pid = ppid[row];
      if (pid < 0) continue;
#pragma unroll
      for (int ni = 0; ni < 2; ++ni) {
        const int col = f0 + wc * 32 + ni * 16 + lr;
        const float s1 = acc1[mi][ni][i];
        const float s3 = acc3[mi][ni][i];
        const float h = s1 * s3 / (1.f + expf(-s1));  // silu(s1)*s3
        hmid[(size_t)pid * kF + col] = f2bf(h);
      }
    }
}

// ---------------------------------------------------------------------------
// GEMM2 (MFMA, 2-phase dbuf): out[t,:] += rw[p] * (hmid_bf16[p] . w2[e][h])
// Tile 128(pairs) x 64(h), BK=64, 16 MFMA/wave/iter. A bf16 direct, B f32->bf16.
// Epilogue: exactly 2 commutative f32 atomics per out element (deterministic).
// ---------------------------------------------------------------------------
__global__ __launch_bounds__(256) void moe_out_mfma(
    const unsigned short* __restrict__ hmid, const float* __restrict__ w2,
    const int* __restrict__ cnt, const int* __restrict__ list,
    const float* __restrict__ rw, float* __restrict__ out) {
  const int e = blockIdx.z;
  const int n = cnt[e];
  const int p0 = blockIdx.y * 128;
  if (p0 >= n) return;
  const int h0 = blockIdx.x * 64;

  __shared__ short As[2][128 * 64];
  __shared__ short Bs[2][64 * 64];
  __shared__ int ppid[128];
  __shared__ int prow[128];

  const int tid = threadIdx.x;
  if (tid < 128) {
    const int idx = p0 + tid;
    const int pid = (idx < n) ? list[e * kT + idx] : -1;
    ppid[tid] = pid;
    prow[tid] = (pid < 0) ? 0 : pid;
  }
  __syncthreads();

  const float* w2e = w2 + (size_t)e * kH * kF;

  const unsigned short* a_src[4];
  int a_sw[4];
#pragma unroll
  for (int i = 0; i < 4; ++i) {
    const int flat = tid + 256 * i;
    const int row = flat >> 3, u = flat & 7;
    a_src[i] = hmid + (size_t)prow[row] * kF + u * 8;
    a_sw[i] = swz(row, u);
  }
  const int brow = tid >> 2, bup = tid & 3;
  const float* b_src = w2e + (size_t)(h0 + brow) * kF + bup * 16;
  const int b_sw0 = swz(brow, 2 * bup), b_sw1 = swz(brow, 2 * bup + 1);

  const int lane = tid & 63, wid = tid >> 6;
  const int wr = wid >> 1, wc = wid & 1;
  const int lr = lane & 15, lq = lane >> 4;

  fx4 acc[4][2];
#pragma unroll
  for (int i = 0; i < 4; ++i)
#pragma unroll
    for (int j = 0; j < 2; ++j) acc[i][j] = (fx4)(0.f);

  bf16x8 aR[4];
  float4 bR[4];
  auto LOAD = [&](int k0) {
#pragma unroll
    for (int i = 0; i < 4; ++i)
      aR[i] = *reinterpret_cast<const bf16x8*>(a_src[i] + k0);
#pragma unroll
    for (int j = 0; j < 4; ++j)
      bR[j] = *reinterpret_cast<const float4*>(b_src + k0 + j * 4);
  };
  auto STORE = [&](int buf) {
    short* Ab = As[buf]; short* Bb = Bs[buf];
#pragma unroll
    for (int i = 0; i < 4; ++i)
      *reinterpret_cast<bf16x8*>(&Ab[a_sw[i]]) = aR[i];
    *reinterpret_cast<bf16x8*>(&Bb[b_sw0]) = pack8(bR[0], bR[1]);
    *reinterpret_cast<bf16x8*>(&Bb[b_sw1]) = pack8(bR[2], bR[3]);
  };

  LOAD(0); STORE(0); __syncthreads();
  int cur = 0;
  constexpr int NIT = kF / 64;
  for (int it = 0; it < NIT; ++it) {
    const bool pf = (it + 1 < NIT);
    if (pf) LOAD((it + 1) * 64);
    const short* Ab = As[cur]; const short* Bb = Bs[cur];
    __builtin_amdgcn_s_setprio(1);
#pragma unroll
    for (int ks = 0; ks < 2; ++ks) {
      bf16x8 a[4], b[2];
#pragma unroll
      for (int mi = 0; mi < 4; ++mi)
        a[mi] = *reinterpret_cast<const bf16x8*>(&Ab[swz(wr * 64 + mi * 16 + lr, ks * 4 + lq)]);
#pragma unroll
      for (int ni = 0; ni < 2; ++ni)
        b[ni] = *reinterpret_cast<const bf16x8*>(&Bb[swz(wc * 32 + ni * 16 + lr, ks * 4 + lq)]);
#pragma unroll
      for (int mi = 0; mi < 4; ++mi)
#pragma unroll
        for (int ni = 0; ni < 2; ++ni)
          acc[mi][ni] = __builtin_amdgcn_mfma_f32_16x16x32_bf16(a[mi], b[ni], acc[mi][ni], 0, 0, 0);
    }
    __builtin_amdgcn_s_setprio(0);
    if (pf) STORE(cur ^ 1);
    __syncthreads();
    cur ^= 1;
  }

#pragma unroll
  for (int mi = 0; mi < 4; ++mi)
#pragma unroll
    for (int i = 0; i < 4; ++i) {
      const int row = wr * 64 + mi * 16 + lq * 4 + i;
      const int pid = ppid[row];
      if (pid < 0) continue;
      const int tok = pid >> 1;
      const float w = rw[pid];
      float* op = out + (size_t)tok * kH + h0 + wc * 32 + lr;
#pragma unroll
      for (int ni = 0; ni < 2; ++ni)
        atomicAdd(&op[ni * 16], w * acc[mi][ni][i]);
    }
}

// ---------------------------------------------------------------------------
extern "C" void kernel_launch(void* const* d_in, const int* in_sizes, int n_in,
                              void* d_out, int out_size, void* d_ws,
                              size_t ws_size, hipStream_t stream) {
  (void)in_sizes; (void)n_in; (void)out_size; (void)ws_size;
  const float* x  = (const float*)d_in[0];  // [1,2048,1024]
  const float* gw = (const float*)d_in[1];  // [8,1024]
  const float* w1 = (const float*)d_in[2];  // [8,3584,1024]
  const float* w2 = (const float*)d_in[3];  // [8,1024,3584]
  const float* w3 = (const float*)d_in[4];  // [8,3584,1024]

  float* out    = (float*)d_out;             // [2048*1024]
  float* logits = out + (size_t)kT * kH;     // [2048*8]

  char* ws = (char*)d_ws;
  int*            cnt  = (int*)(ws + OFF_CNT);
  int*            list = (int*)(ws + OFF_LIST);
  float*          rw   = (float*)(ws + OFF_RW);
  unsigned short* hmid = (unsigned short*)(ws + OFF_HMID);

  hipMemsetAsync(out, 0, (size_t)kT * kH * sizeof(float), stream);
  hipMemsetAsync(cnt, 0, kE * sizeof(int), stream);

  router_kernel<<<kT, 256, 0, stream>>>(x, gw, logits, cnt, list, rw);

  dim3 g1(kF / 64, kT / 128, kE);   // (56, 16, 8)
  moe_mid_mfma<<<g1, 256, 0, stream>>>(x, w1, w3, cnt, list, hmid);

  dim3 g2(kH / 64, kT / 128, kE);   // (16, 16, 8)
  moe_out_mfma<<<g2, 256, 0, stream>>>(hmid, w2, cnt, list, rw, out);
}